// Round 26
// baseline (167.645 us; speedup 1.0000x reference)
//
#include <hip/hip_runtime.h>

#define R_ 4096
#define S_ 64
#define H_ 256
#define N_ (R_ * S_)
#define FARD 1e10f

typedef __attribute__((ext_vector_type(4))) float f32x4;
typedef __attribute__((ext_vector_type(8))) short short8;
typedef __attribute__((ext_vector_type(8))) int i32x8;

union U8 { short8 s; uint4 u; };
union V8 { i32x8 v; uint4 q[2]; };

__device__ __forceinline__ unsigned int cvt_pk_bf16(float lo, float hi) {
    unsigned int r;
    asm("v_cvt_pk_bf16_f32 %0, %1, %2" : "=v"(r) : "v"(lo), "v"(hi));
    return r;
}
__device__ __forceinline__ unsigned short f2bf(float f) {
    unsigned int x = __float_as_uint(f);
    x += 0x7fffu + ((x >> 16) & 1u);          // RNE
    return (unsigned short)(x >> 16);
}
__device__ __forceinline__ unsigned int pk4_fp8(float a0, float a1, float a2, float a3) {
    unsigned int lo, hi;
    asm("v_cvt_pk_fp8_f32 %0, %1, %2" : "=v"(lo) : "v"(a0), "v"(a1));
    asm("v_cvt_pk_fp8_f32 %0, %1, %2" : "=v"(hi) : "v"(a2), "v"(a3));
    return (lo & 0xffffu) | (hi << 16);
}
__device__ __forceinline__ unsigned char f2fp8(float v) {
    unsigned int r;
    asm("v_cvt_pk_fp8_f32 %0, %1, %2" : "=v"(r) : "v"(v), "v"(0.0f));
    return (unsigned char)(r & 0xff);
}
__device__ __forceinline__ float sigmoidf_(float x) { return 1.0f / (1.0f + expf(-x)); }

typedef const __attribute__((address_space(1))) unsigned char* gas1;
typedef __attribute__((address_space(3))) unsigned char* las3;
// async DMA 64KB global->LDS with 1024 threads (4 x 16B); layout pre-baked (m173).
__device__ __forceinline__ void stage64k(const unsigned char* g, unsigned char* l, int tid) {
#pragma unroll
    for (int i = 0; i < 4; ++i)
        __builtin_amdgcn_global_load_lds((gas1)(g + i * 16384 + tid * 16),
                                         (las3)(l + i * 16384 + tid * 16), 16, 0, 0);
}

// FRAGMENT-MAJOR act (2 rays = 128 samples): 16 tiles of 2KB, tile = mt_abs*2+s.
// Byte (h*1024 + l*16 + b) of tile holds act[sample = mt_abs*16 + (l&15)]
// [k = s*128 + (l>>4)*32 + h*16 + b]. (R25 layout x2 m-tiles; round-trip verified.)
// store: thread (m0,q) of wave (wq,sh) holds neurons n0=wq*32+nt*16+4q of
// samples sh*64+mt*16+m0.
__device__ __forceinline__ void store_act_frag(unsigned char* act, const unsigned int pk[8],
                                               int lane, int wq, int sh)
{
    const int m0 = lane & 15;
    const int q  = lane >> 4;
    const int sp = wq >> 2;            // k-half of this wave's neurons
    const int c4 = (wq & 3) << 4;      // lane-group within tile
#pragma unroll
    for (int nt = 0; nt < 2; ++nt)
#pragma unroll
        for (int mt = 0; mt < 4; ++mt)
            *(unsigned int*)(act + ((sh * 4 + mt) * 2 + sp) * 2048 + nt * 1024 +
                             (c4 + m0) * 16 + 4 * q) = pk[nt * 4 + mt];
}

// ---- hidden layer, dbuf: stage NEXT panel at phase start (overlaps compute),
// compute from wcur, sync, store act in place, sync (drain).
__device__ void hidden_layer(unsigned char* act, unsigned char* wcur, unsigned char* wnext,
                             const unsigned char* __restrict__ next_panel,
                             const float* __restrict__ bias, int lane, int wq, int sh, int tid)
{
    const int m0 = lane & 15;
    const int q  = lane >> 4;
    const int nw = wq << 5;            // 32 neurons per wave

    if (next_panel) stage64k(next_panel, wnext, tid);   // full-phase overlap

    f32x4 acc[2][4];                   // 32 AGPR
#pragma unroll
    for (int nt = 0; nt < 2; ++nt) {
        const float4 bv = *(const float4*)&bias[nw + nt * 16 + 4 * q];
#pragma unroll
        for (int mt = 0; mt < 4; ++mt) {
            acc[nt][mt][0] = bv.x; acc[nt][mt][1] = bv.y;
            acc[nt][mt][2] = bv.z; acc[nt][mt][3] = bv.w;
        }
    }

    __builtin_amdgcn_s_setprio(1);
#pragma unroll
    for (int s = 0; s < 2; ++s) {                  // K = 2 steps of 128
        V8 A[2];
#pragma unroll
        for (int nt = 0; nt < 2; ++nt) {
            const int t = wq * 4 + nt * 2 + s;
            A[nt].q[0] = *(const uint4*)(wcur + t * 2048 + lane * 16);
            A[nt].q[1] = *(const uint4*)(wcur + t * 2048 + 1024 + lane * 16);
        }
#pragma unroll
        for (int mt = 0; mt < 4; ++mt) {
            V8 B;
            const int bt = ((sh * 4 + mt) * 2 + s) * 2048;
            B.q[0] = *(const uint4*)(act + bt + lane * 16);
            B.q[1] = *(const uint4*)(act + bt + 1024 + lane * 16);
#pragma unroll
            for (int nt = 0; nt < 2; ++nt)
                acc[nt][mt] = __builtin_amdgcn_mfma_scale_f32_16x16x128_f8f6f4(
                    A[nt].v, B.v, acc[nt][mt], 0, 0,
                    0, 0x7F7F7F7Fu, 0, 0x7F7F7F7Fu);   // E8M0 127 = x1.0
        }
    }
    __builtin_amdgcn_s_setprio(0);
    __syncthreads();                   // act reads complete (in-place hazard)
    unsigned int pk[8];
#pragma unroll
    for (int nt = 0; nt < 2; ++nt)
#pragma unroll
        for (int mt = 0; mt < 4; ++mt) {
            f32x4 a = acc[nt][mt];
            pk[nt * 4 + mt] = pk4_fp8(fmaxf(a[0], 0.f), fmaxf(a[1], 0.f),
                                      fmaxf(a[2], 0.f), fmaxf(a[3], 0.f));
        }
    store_act_frag(act, pk, lane, wq, sh);
    __syncthreads();                   // act visible; DMA drained
}

// ---- input layer COMPUTE ONLY: bf16 MFMA -> 8 packed fp8 words in regs.
__device__ void input_compute(const float* __restrict__ pts, const float* __restrict__ drs,
                              const float* __restrict__ tv,
                              const short* __restrict__ WinT, const float* __restrict__ bin,
                              unsigned int pk[8], int base, int lane, int wq, int sh)
{
    const int m0 = lane & 15;
    const int q  = lane >> 4;
    const int nw = wq << 5;

    short8 B[4];
#pragma unroll
    for (int mt = 0; mt < 4; ++mt) {
        U8 ub;
        if (q == 0) {
            const int s = base + sh * 64 + mt * 16 + m0;
            float p0 = pts[s * 3 + 0], p1 = pts[s * 3 + 1], p2 = pts[s * 3 + 2];
            float e0 = drs[s * 3 + 0], e1 = drs[s * 3 + 1], e2 = drs[s * 3 + 2];
            float t  = tv[s];
            ub.u = make_uint4(cvt_pk_bf16(p0, p1), cvt_pk_bf16(p2, e0),
                              cvt_pk_bf16(e1, e2), cvt_pk_bf16(t, 0.f));
        } else {
            ub.u = make_uint4(0, 0, 0, 0);
        }
        B[mt] = ub.s;
    }

    f32x4 acc[2][4];
#pragma unroll
    for (int nt = 0; nt < 2; ++nt) {
        const float4 bv = *(const float4*)&bin[nw + nt * 16 + 4 * q];
#pragma unroll
        for (int mt = 0; mt < 4; ++mt) {
            acc[nt][mt][0] = bv.x; acc[nt][mt][1] = bv.y;
            acc[nt][mt][2] = bv.z; acc[nt][mt][3] = bv.w;
        }
    }
#pragma unroll
    for (int nt = 0; nt < 2; ++nt) {
        // rows k>=INK of WinT are zero, so q!=0 slices contribute 0
        short8 A = *(const short8*)&WinT[(nw + nt * 16 + m0) * 32 + 8 * q];
#pragma unroll
        for (int mt = 0; mt < 4; ++mt)
            acc[nt][mt] = __builtin_amdgcn_mfma_f32_16x16x32_bf16(A, B[mt], acc[nt][mt], 0, 0, 0);
    }
#pragma unroll
    for (int nt = 0; nt < 2; ++nt)
#pragma unroll
        for (int mt = 0; mt < 4; ++mt) {
            f32x4 a = acc[nt][mt];
            pk[nt * 4 + mt] = pk4_fp8(fmaxf(a[0], 0.f), fmaxf(a[1], 0.f),
                                      fmaxf(a[2], 0.f), fmaxf(a[3], 0.f));
        }
}

// ---- output layer via scaled 16x16x128: waves 0..7, wave wv -> m-tile wv.
template <int OUTD>
__device__ void out_mfma(const unsigned char* act, const unsigned char* __restrict__ WoT,
                         const float* __restrict__ bout, float* o, int lane, int wv)
{
    const int q = lane >> 4;

    f32x4 acc = {0.f, 0.f, 0.f, 0.f};
#pragma unroll
    for (int s = 0; s < 2; ++s) {
        V8 A, B;
        A.q[0] = *(const uint4*)(WoT + s * 2048 + lane * 16);
        A.q[1] = *(const uint4*)(WoT + s * 2048 + 1024 + lane * 16);
        B.q[0] = *(const uint4*)(act + (wv * 2 + s) * 2048 + lane * 16);
        B.q[1] = *(const uint4*)(act + (wv * 2 + s) * 2048 + 1024 + lane * 16);
        acc = __builtin_amdgcn_mfma_scale_f32_16x16x128_f8f6f4(
            A.v, B.v, acc, 0, 0, 0, 0x7F7F7F7Fu, 0, 0x7F7F7F7Fu);
    }
    if (q == 0) {
        o[0] = acc[0] + bout[0]; o[1] = acc[1] + bout[1];
        o[2] = acc[2] + bout[2]; o[3] = acc[3] + bout[3];
    }
    if (OUTD == 5 && q == 1) o[4] = acc[0] + bout[4];
}

// 1024 threads = 16 waves, 2 rays/block. LDS: 2x64K wbuf dbuf + 32K act = 160KB
// exactly -> 1 block/CU, 4 waves/SIMD; weight DMA traffic halved + full overlap.
__global__ __launch_bounds__(1024, 4) void nerf_kernel(
    const float* __restrict__ points, const float* __restrict__ dirs,
    const float* __restrict__ z_vals, const float* __restrict__ timev,
    const float* __restrict__ sbin, const float* __restrict__ sbh, const float* __restrict__ sbout,
    const float* __restrict__ dbin, const float* __restrict__ dbh, const float* __restrict__ dbout,
    const unsigned char* __restrict__ wsb,
    float* __restrict__ out)
{
    __shared__ __align__(16) unsigned char wbuf0[65536];
    __shared__ __align__(16) unsigned char wbuf1[65536];
    __shared__ __align__(16) unsigned char act[32768];   // 128 samples, in-place

    const int tid  = threadIdx.x;
    const int lane = tid & 63;
    const int wv   = tid >> 6;        // 0..15
    const int wq   = wv & 7;          // neuron-group wave
    const int sh   = wv >> 3;         // sample-half
    const int base = blockIdx.x * 128;

    const unsigned char* sW8   = wsb;                    // 3*64K fp8 fragment-major
    const unsigned char* dW8   = wsb + 196608;
    const short* sWinT = (const short*)(wsb + 393216);   // 256*32 bf16
    const short* dWinT = (const short*)(wsb + 409600);
    const unsigned char* sWoT8 = wsb + 425984;           // 2 tiles fragment-major
    const unsigned char* dWoT8 = wsb + 430080;

    // ---- static MLP ----
    stage64k(sW8 + 0 * 65536, wbuf0, tid);
    {
        unsigned int pk[8];
        input_compute(points, dirs, timev, sWinT, sbin, pk, base, lane, wq, sh);
        store_act_frag(act, pk, lane, wq, sh);
    }
    __syncthreads();                                     // act ready; w0 staged

    hidden_layer(act, wbuf0, wbuf1, sW8 + 1 * 65536, sbh + 0 * H_, lane, wq, sh, tid);
    hidden_layer(act, wbuf1, wbuf0, sW8 + 2 * 65536, sbh + 1 * H_, lane, wq, sh, tid);
    hidden_layer(act, wbuf0, wbuf1, dW8 + 0 * 65536, sbh + 2 * H_, lane, wq, sh, tid);

    // ---- phase-merge: dyn-input compute (no act dep) overlaps static-out ----
    float so[4];
    unsigned int dpk[8];
    input_compute(points, dirs, timev, dWinT, dbin, dpk, base, lane, wq, sh);
    if (wv < 8) out_mfma<4>(act, sWoT8, sbout, so, lane, wv);
    __syncthreads();                                     // out4's act reads done
    store_act_frag(act, dpk, lane, wq, sh);
    __syncthreads();                                     // dyn act ready

    // ---- dynamic MLP (dW0 staged in wbuf1 during L2) ----
    hidden_layer(act, wbuf1, wbuf0, dW8 + 1 * 65536, dbh + 0 * H_, lane, wq, sh, tid);
    hidden_layer(act, wbuf0, wbuf1, dW8 + 2 * 65536, dbh + 1 * H_, lane, wq, sh, tid);
    hidden_layer(act, wbuf1, wbuf0, nullptr,         dbh + 2 * H_, lane, wq, sh, tid);

    float dox[5];
    if (wv < 8) out_mfma<5>(act, dWoT8, dbout, dox, lane, wv);
    __syncthreads();                                     // act reads done; act dead

    // ---- stash so/do into dead act (float layout [128][9]) ----
    float* mixb = (float*)act;
    if (wv < 8) {
        const int m0 = lane & 15;
        const int q  = lane >> 4;
        const int m  = wv * 16 + m0;
        if (q == 0) {
            mixb[m * 9 + 0] = so[0];  mixb[m * 9 + 1] = so[1];
            mixb[m * 9 + 2] = so[2];  mixb[m * 9 + 3] = so[3];
            mixb[m * 9 + 4] = dox[0]; mixb[m * 9 + 5] = dox[1];
            mixb[m * 9 + 6] = dox[2]; mixb[m * 9 + 7] = dox[3];
        }
        if (q == 1) mixb[m * 9 + 8] = dox[4];
    }
    __syncthreads();

    // ---- mix + fused render: waves 0-1, one ray each; lane = sample
    if (tid < 128) {
        const int sl  = tid & 63;
        const int ray = blockIdx.x * 2 + (tid >> 6);
        float so0 = mixb[tid * 9 + 0], so1 = mixb[tid * 9 + 1];
        float so2 = mixb[tid * 9 + 2], so3 = mixb[tid * 9 + 3];
        float d0 = mixb[tid * 9 + 4], d1 = mixb[tid * 9 + 5], d2 = mixb[tid * 9 + 6];
        float d3 = mixb[tid * 9 + 7], d4 = mixb[tid * 9 + 8];

        float bw  = sigmoidf_(d4);
        float omb = 1.f - bw;
        float sigma = omb * so0 + bw * d0;
        float cr = omb * sigmoidf_(so1) + bw * sigmoidf_(d1);
        float cg = omb * sigmoidf_(so2) + bw * sigmoidf_(d2);
        float cb = omb * sigmoidf_(so3) + bw * sigmoidf_(d3);

        float z  = z_vals[base + tid];
        float zn = __shfl_down(z, 1);
        float delta = (sl < 63) ? (zn - z) : FARD;
        float ex    = fminf(-sigma * delta, 60.0f);   // finite where ref overflows
        float alpha = 1.f - expf(ex);
        float f     = 1.f - alpha + 1e-10f;
        float p = f;
#pragma unroll
        for (int d = 1; d < 64; d <<= 1) {
            float pu = __shfl_up(p, d);
            if (sl >= d) p *= pu;
        }
        float T = (sl == 0) ? 1.f : __shfl_up(p, 1);
        float w = alpha * T;

        float* rgb_map   = out;
        float* depth_map = out + R_ * 3;
        float* weights   = out + R_ * 4;
        float* swei      = weights + N_;
        float* dwei      = swei + N_;
        weights[base + tid] = w;
        swei[base + tid]    = omb * w;
        dwei[base + tid]    = bw * w;

        float c0 = w * cr, c1 = w * cg, c2 = w * cb, dd = w * z;
#pragma unroll
        for (int d = 32; d >= 1; d >>= 1) {
            c0 += __shfl_down(c0, d);
            c1 += __shfl_down(c1, d);
            c2 += __shfl_down(c2, d);
            dd += __shfl_down(dd, d);
        }
        if (sl == 0) {
            rgb_map[ray * 3 + 0] = c0;
            rgb_map[ray * 3 + 1] = c1;
            rgb_map[ray * 3 + 2] = c2;
            depth_map[ray] = dd;
        }
    }
}

// ---- prep (IDENTICAL to R25 — verified layouts). Layout (bytes):
// [0)      sW8  3*64K fp8 FRAGMENT-MAJOR
// [196608) dW8  same
// [393216) sWinT 256*32 bf16 (k>=6 zero-padded)
// [409600) dWinT 256*32 bf16 (k>=7 zero-padded)
// [425984) sWoT8 2 tiles x 2KB fragment-major (o>=4 zero-padded)
// [430080) dWoT8 same (o>=5 zero-padded)
__global__ void convert_weights(const float* __restrict__ sWh, const float* __restrict__ dWh,
                                const float* __restrict__ sWin, const float* __restrict__ dWin,
                                const float* __restrict__ sWout, const float* __restrict__ dWout,
                                unsigned char* __restrict__ ws)
{
    int idx = blockIdx.x * 256 + threadIdx.x;      // 417792 total
    if (idx < 393216) {
        int which = idx >= 196608;
        int rem   = which ? idx - 196608 : idx;
        int l = rem >> 16, e = rem & 65535;
        int t = e >> 11, r2 = e & 2047;
        int h = r2 >> 10, r3 = r2 & 1023;
        int ln = r3 >> 4, b = r3 & 15;
        int wv = t >> 2, nt = (t >> 1) & 1, s = t & 1;
        int n = wv * 32 + nt * 16 + (ln & 15);
        int k = s * 128 + (ln >> 4) * 32 + h * 16 + b;
        const float* W = which ? dWh : sWh;
        ws[idx] = f2fp8(W[l * 65536 + k * 256 + n]);
    } else if (idx < 409600) {
        int j = idx - 393216;                      // [0, 16384)
        int which = j >= 8192;
        int e = j & 8191;
        int n = e >> 5, k = e & 31;
        int ink = which ? 7 : 6;
        const float* W = which ? dWin : sWin;
        float v = (k < ink) ? W[k * 256 + n] : 0.f;
        ((short*)(ws + 393216))[j] = (short)f2bf(v);
    } else {
        int j = idx - 409600;                      // [0, 8192)
        int which = j >= 4096;
        int e = j & 4095;
        int s = e >> 11, r2 = e & 2047;
        int h = r2 >> 10, r3 = r2 & 1023;
        int ln = r3 >> 4, b = r3 & 15;
        int o = ln & 15;
        int k = s * 128 + (ln >> 4) * 32 + h * 16 + b;
        int outd = which ? 5 : 4;
        const float* W = which ? dWout : sWout;
        float v = (o < outd) ? W[k * outd + o] : 0.f;
        ws[425984 + (which ? 4096 : 0) + e] = f2fp8(v);
    }
}

extern "C" void kernel_launch(void* const* d_in, const int* in_sizes, int n_in,
                              void* d_out, int out_size, void* d_ws, size_t ws_size,
                              hipStream_t stream)
{
    const float* points = (const float*)d_in[0];
    const float* dirs   = (const float*)d_in[1];
    const float* z_vals = (const float*)d_in[2];
    const float* timev  = (const float*)d_in[3];
    const float* sWin   = (const float*)d_in[4];
    const float* sbin   = (const float*)d_in[5];
    const float* sWh    = (const float*)d_in[6];
    const float* sbh    = (const float*)d_in[7];
    const float* sWout  = (const float*)d_in[8];
    const float* sbout  = (const float*)d_in[9];
    const float* dWin   = (const float*)d_in[10];
    const float* dbin   = (const float*)d_in[11];
    const float* dWh    = (const float*)d_in[12];
    const float* dbh    = (const float*)d_in[13];
    const float* dWout  = (const float*)d_in[14];
    const float* dbout  = (const float*)d_in[15];

    unsigned char* wsb = (unsigned char*)d_ws;

    convert_weights<<<1632, 256, 0, stream>>>(sWh, dWh, sWin, dWin, sWout, dWout, wsb);

    nerf_kernel<<<R_ / 2, 1024, 0, stream>>>(
        points, dirs, z_vals, timev,
        sbin, sbh, sbout, dbin, dbh, dbout,
        wsb, (float*)d_out);
}

// Round 27
// 164.016 us; speedup vs baseline: 1.0221x; 1.0221x over previous
//
#include <hip/hip_runtime.h>

#define R_ 4096
#define S_ 64
#define H_ 256
#define N_ (R_ * S_)
#define FARD 1e10f

typedef __attribute__((ext_vector_type(4))) float f32x4;
typedef __attribute__((ext_vector_type(8))) short short8;
typedef __attribute__((ext_vector_type(8))) int i32x8;

union U8 { short8 s; uint4 u; };
union V8 { i32x8 v; uint4 q[2]; };

__device__ __forceinline__ unsigned int cvt_pk_bf16(float lo, float hi) {
    unsigned int r;
    asm("v_cvt_pk_bf16_f32 %0, %1, %2" : "=v"(r) : "v"(lo), "v"(hi));
    return r;
}
__device__ __forceinline__ unsigned short f2bf(float f) {
    unsigned int x = __float_as_uint(f);
    x += 0x7fffu + ((x >> 16) & 1u);          // RNE
    return (unsigned short)(x >> 16);
}
__device__ __forceinline__ unsigned int pk4_fp8(float a0, float a1, float a2, float a3) {
    unsigned int lo, hi;
    asm("v_cvt_pk_fp8_f32 %0, %1, %2" : "=v"(lo) : "v"(a0), "v"(a1));
    asm("v_cvt_pk_fp8_f32 %0, %1, %2" : "=v"(hi) : "v"(a2), "v"(a3));
    return (lo & 0xffffu) | (hi << 16);
}
__device__ __forceinline__ unsigned char f2fp8(float v) {
    unsigned int r;
    asm("v_cvt_pk_fp8_f32 %0, %1, %2" : "=v"(r) : "v"(v), "v"(0.0f));
    return (unsigned char)(r & 0xff);
}
__device__ __forceinline__ float sigmoidf_(float x) { return 1.0f / (1.0f + expf(-x)); }

typedef const __attribute__((address_space(1))) unsigned char* gas1;
typedef __attribute__((address_space(3))) unsigned char* las3;
// async DMA 64KB global->LDS with 512 threads; layout pre-baked (m173).
__device__ __forceinline__ void stage64k(const unsigned char* g, unsigned char* l, int tid) {
#pragma unroll
    for (int i = 0; i < 8; ++i)
        __builtin_amdgcn_global_load_lds((gas1)(g + i * 8192 + tid * 16),
                                         (las3)(l + i * 8192 + tid * 16), 16, 0, 0);
}

// FRAGMENT-MAJOR act layout (R25-verified): 8 tiles of 2KB, tile = mt*2 + s.
// store 8 packed words (neurons n0=wv*32+nt*16+4q of samples mt*16+m0)
__device__ __forceinline__ void store_act_frag(unsigned char* act, const unsigned int pk[8],
                                               int lane, int wv)
{
    const int m0 = lane & 15;
    const int q  = lane >> 4;
    const int sp = wv >> 2;            // k-half of this wave's neurons
    const int c4 = (wv & 3) << 4;      // lane-group within tile
#pragma unroll
    for (int nt = 0; nt < 2; ++nt)
#pragma unroll
        for (int mt = 0; mt < 4; ++mt)
            *(unsigned int*)(act + (mt * 2 + sp) * 2048 + nt * 1024 +
                             (c4 + m0) * 16 + 4 * q) = pk[nt * 4 + mt];
}

// ---- hidden layer via MX-scaled fp8 MFMA 16x16x128, SELF-STAGED (R27):
// wave wv's weights = wbuf[wv*8192 .. +8KB] (tiles wv*4..wv*4+3), read by no
// other wave -> after its MFMAs each wave DMAs its own next-panel section.
// sync1 becomes a RAW lgkmcnt-only barrier (no vmcnt drain, T4) so the DMA
// stays in flight across pack/store; sync2 (__syncthreads) drains it.
__device__ void hidden_layer(unsigned char* act, unsigned char* wbuf,
                             const unsigned char* __restrict__ next_panel,
                             const float* __restrict__ bias, int lane, int wv, int tid)
{
    const int m0 = lane & 15;
    const int q  = lane >> 4;
    const int nw = wv << 5;            // 32 neurons per wave

    f32x4 acc[2][4];                   // 32 AGPR
#pragma unroll
    for (int nt = 0; nt < 2; ++nt) {
        const float4 bv = *(const float4*)&bias[nw + nt * 16 + 4 * q];
#pragma unroll
        for (int mt = 0; mt < 4; ++mt) {
            acc[nt][mt][0] = bv.x; acc[nt][mt][1] = bv.y;
            acc[nt][mt][2] = bv.z; acc[nt][mt][3] = bv.w;
        }
    }

    __builtin_amdgcn_s_setprio(1);
#pragma unroll
    for (int s = 0; s < 2; ++s) {                  // K = 2 steps of 128
        V8 A[2];
#pragma unroll
        for (int nt = 0; nt < 2; ++nt) {
            const int t = wv * 4 + nt * 2 + s;
            A[nt].q[0] = *(const uint4*)(wbuf + t * 2048 + lane * 16);
            A[nt].q[1] = *(const uint4*)(wbuf + t * 2048 + 1024 + lane * 16);
        }
#pragma unroll
        for (int mt = 0; mt < 4; ++mt) {
            V8 B;
            B.q[0] = *(const uint4*)(act + (mt * 2 + s) * 2048 + lane * 16);
            B.q[1] = *(const uint4*)(act + (mt * 2 + s) * 2048 + 1024 + lane * 16);
#pragma unroll
            for (int nt = 0; nt < 2; ++nt)
                acc[nt][mt] = __builtin_amdgcn_mfma_scale_f32_16x16x128_f8f6f4(
                    A[nt].v, B.v, acc[nt][mt], 0, 0,
                    0, 0x7F7F7F7Fu, 0, 0x7F7F7F7Fu);   // E8M0 127 = x1.0
        }
    }
    __builtin_amdgcn_s_setprio(0);

    // self-stage own 8KB next-panel section (this wave's reads are retired)
    if (next_panel) {
        const unsigned char* g = next_panel + wv * 8192;
        unsigned char* l = wbuf + wv * 8192;
#pragma unroll
        for (int i = 0; i < 8; ++i)
            __builtin_amdgcn_global_load_lds((gas1)(g + i * 1024 + lane * 16),
                                             (las3)(l + i * 1024 + lane * 16), 16, 0, 0);
    }
    // raw barrier: order act reads vs writes (LDS-only hazard) WITHOUT vmcnt drain
    asm volatile("s_waitcnt lgkmcnt(0)\n\ts_barrier" ::: "memory");
    __builtin_amdgcn_sched_barrier(0);             // rule #18: pin following LDS writes

    unsigned int pk[8];
#pragma unroll
    for (int nt = 0; nt < 2; ++nt)
#pragma unroll
        for (int mt = 0; mt < 4; ++mt) {
            f32x4 a = acc[nt][mt];
            pk[nt * 4 + mt] = pk4_fp8(fmaxf(a[0], 0.f), fmaxf(a[1], 0.f),
                                      fmaxf(a[2], 0.f), fmaxf(a[3], 0.f));
        }
    store_act_frag(act, pk, lane, wv);
    __syncthreads();                   // act visible; DMA drained (vmcnt(0))
}

// ---- input layer COMPUTE ONLY: bf16 MFMA -> 8 packed fp8 words in regs.
__device__ void input_compute(const float* __restrict__ pts, const float* __restrict__ drs,
                              const float* __restrict__ tv,
                              const short* __restrict__ WinT, const float* __restrict__ bin,
                              unsigned int pk[8], int base, int lane, int wv)
{
    const int m0 = lane & 15;
    const int q  = lane >> 4;
    const int nw = wv << 5;

    short8 B[4];
#pragma unroll
    for (int mt = 0; mt < 4; ++mt) {
        U8 ub;
        if (q == 0) {
            const int s = base + mt * 16 + m0;
            float p0 = pts[s * 3 + 0], p1 = pts[s * 3 + 1], p2 = pts[s * 3 + 2];
            float e0 = drs[s * 3 + 0], e1 = drs[s * 3 + 1], e2 = drs[s * 3 + 2];
            float t  = tv[s];
            ub.u = make_uint4(cvt_pk_bf16(p0, p1), cvt_pk_bf16(p2, e0),
                              cvt_pk_bf16(e1, e2), cvt_pk_bf16(t, 0.f));
        } else {
            ub.u = make_uint4(0, 0, 0, 0);
        }
        B[mt] = ub.s;
    }

    f32x4 acc[2][4];
#pragma unroll
    for (int nt = 0; nt < 2; ++nt) {
        const float4 bv = *(const float4*)&bin[nw + nt * 16 + 4 * q];
#pragma unroll
        for (int mt = 0; mt < 4; ++mt) {
            acc[nt][mt][0] = bv.x; acc[nt][mt][1] = bv.y;
            acc[nt][mt][2] = bv.z; acc[nt][mt][3] = bv.w;
        }
    }
#pragma unroll
    for (int nt = 0; nt < 2; ++nt) {
        // rows k>=INK of WinT are zero, so q!=0 slices contribute 0
        short8 A = *(const short8*)&WinT[(nw + nt * 16 + m0) * 32 + 8 * q];
#pragma unroll
        for (int mt = 0; mt < 4; ++mt)
            acc[nt][mt] = __builtin_amdgcn_mfma_f32_16x16x32_bf16(A, B[mt], acc[nt][mt], 0, 0, 0);
    }
#pragma unroll
    for (int nt = 0; nt < 2; ++nt)
#pragma unroll
        for (int mt = 0; mt < 4; ++mt) {
            f32x4 a = acc[nt][mt];
            pk[nt * 4 + mt] = pk4_fp8(fmaxf(a[0], 0.f), fmaxf(a[1], 0.f),
                                      fmaxf(a[2], 0.f), fmaxf(a[3], 0.f));
        }
}

// ---- output layer via scaled 16x16x128 (2 MFMA): waves 0-3, wave wv -> m-tile wv.
template <int OUTD>
__device__ void out_mfma(const unsigned char* act, const unsigned char* __restrict__ WoT,
                         const float* __restrict__ bout, float* o, int lane, int wv)
{
    const int q = lane >> 4;

    f32x4 acc = {0.f, 0.f, 0.f, 0.f};
#pragma unroll
    for (int s = 0; s < 2; ++s) {
        V8 A, B;
        A.q[0] = *(const uint4*)(WoT + s * 2048 + lane * 16);
        A.q[1] = *(const uint4*)(WoT + s * 2048 + 1024 + lane * 16);
        B.q[0] = *(const uint4*)(act + (wv * 2 + s) * 2048 + lane * 16);
        B.q[1] = *(const uint4*)(act + (wv * 2 + s) * 2048 + 1024 + lane * 16);
        acc = __builtin_amdgcn_mfma_scale_f32_16x16x128_f8f6f4(
            A.v, B.v, acc, 0, 0, 0, 0x7F7F7F7Fu, 0, 0x7F7F7F7Fu);
    }
    if (q == 0) {
        o[0] = acc[0] + bout[0]; o[1] = acc[1] + bout[1];
        o[2] = acc[2] + bout[2]; o[3] = acc[3] + bout[3];
    }
    if (OUTD == 5 && q == 1) o[4] = acc[0] + bout[4];
}

// 512 threads = 8 waves x 32 neurons. LDS: 64K wbuf + 16K act = 80KB exactly
// -> 2 blocks/CU = 4 waves/SIMD.
__global__ __launch_bounds__(512, 4) void nerf_kernel(
    const float* __restrict__ points, const float* __restrict__ dirs,
    const float* __restrict__ z_vals, const float* __restrict__ timev,
    const float* __restrict__ sbin, const float* __restrict__ sbh, const float* __restrict__ sbout,
    const float* __restrict__ dbin, const float* __restrict__ dbh, const float* __restrict__ dbout,
    const unsigned char* __restrict__ wsb,
    float* __restrict__ out)
{
    __shared__ __align__(16) unsigned char wbuf[65536];
    __shared__ __align__(16) unsigned char act[64 * H_];   // 16KB, in-place

    const int tid  = threadIdx.x;
    const int lane = tid & 63;
    const int wv   = tid >> 6;
    const int ray  = blockIdx.x;
    const int base = ray * 64;

    const unsigned char* sW8   = wsb;                    // 3*64K fp8 fragment-major
    const unsigned char* dW8   = wsb + 196608;
    const short* sWinT = (const short*)(wsb + 393216);   // 256*32 bf16
    const short* dWinT = (const short*)(wsb + 409600);
    const unsigned char* sWoT8 = wsb + 425984;           // 2 tiles fragment-major
    const unsigned char* dWoT8 = wsb + 430080;

    // ---- static MLP ----
    stage64k(sW8 + 0 * 65536, wbuf, tid);                // s_h0 (overlaps input)
    {
        unsigned int pk[8];
        input_compute(points, dirs, timev, sWinT, sbin, pk, base, lane, wv);
        store_act_frag(act, pk, lane, wv);
    }
    __syncthreads();                                     // act ready; s_h0 staged

    hidden_layer(act, wbuf, sW8 + 1 * 65536, sbh + 0 * H_, lane, wv, tid);
    hidden_layer(act, wbuf, sW8 + 2 * 65536, sbh + 1 * H_, lane, wv, tid);
    hidden_layer(act, wbuf, dW8 + 0 * 65536, sbh + 2 * H_, lane, wv, tid);

    // ---- phase-merge: dyn-input compute (no act dep) overlaps static-out ----
    float so[4];
    unsigned int dpk[8];
    input_compute(points, dirs, timev, dWinT, dbin, dpk, base, lane, wv);
    if (wv < 4) out_mfma<4>(act, sWoT8, sbout, so, lane, wv);
    __syncthreads();                                     // out4's act reads done
    store_act_frag(act, dpk, lane, wv);
    __syncthreads();                                     // dyn act ready (d_h0 staged)

    // ---- dynamic MLP ----
    hidden_layer(act, wbuf, dW8 + 1 * 65536, dbh + 0 * H_, lane, wv, tid);
    hidden_layer(act, wbuf, dW8 + 2 * 65536, dbh + 1 * H_, lane, wv, tid);
    hidden_layer(act, wbuf, nullptr,         dbh + 2 * H_, lane, wv, tid);

    float dox[5];
    if (wv < 4) out_mfma<5>(act, dWoT8, dbout, dox, lane, wv);
    __syncthreads();                                     // act reads done; act now dead

    // ---- stash so/do into dead act (float layout [64][9]) ----
    float* mixb = (float*)act;
    if (wv < 4) {
        const int m0 = lane & 15;
        const int q  = lane >> 4;
        const int m  = (wv << 4) + m0;
        if (q == 0) {
            mixb[m * 9 + 0] = so[0];  mixb[m * 9 + 1] = so[1];
            mixb[m * 9 + 2] = so[2];  mixb[m * 9 + 3] = so[3];
            mixb[m * 9 + 4] = dox[0]; mixb[m * 9 + 5] = dox[1];
            mixb[m * 9 + 6] = dox[2]; mixb[m * 9 + 7] = dox[3];
        }
        if (q == 1) mixb[m * 9 + 8] = dox[4];
    }
    __syncthreads();

    // ---- mix + fused render: wave 0, lane s = sample
    if (tid < 64) {
        const int s = tid;
        float so0 = mixb[s * 9 + 0], so1 = mixb[s * 9 + 1];
        float so2 = mixb[s * 9 + 2], so3 = mixb[s * 9 + 3];
        float d0 = mixb[s * 9 + 4], d1 = mixb[s * 9 + 5], d2 = mixb[s * 9 + 6];
        float d3 = mixb[s * 9 + 7], d4 = mixb[s * 9 + 8];

        float bw  = sigmoidf_(d4);
        float omb = 1.f - bw;
        float sigma = omb * so0 + bw * d0;
        float cr = omb * sigmoidf_(so1) + bw * sigmoidf_(d1);
        float cg = omb * sigmoidf_(so2) + bw * sigmoidf_(d2);
        float cb = omb * sigmoidf_(so3) + bw * sigmoidf_(d3);

        float z  = z_vals[base + s];
        float zn = __shfl_down(z, 1);
        float delta = (s < 63) ? (zn - z) : FARD;
        float ex    = fminf(-sigma * delta, 60.0f);   // finite where ref overflows
        float alpha = 1.f - expf(ex);
        float f     = 1.f - alpha + 1e-10f;
        float p = f;
#pragma unroll
        for (int d = 1; d < 64; d <<= 1) {
            float pu = __shfl_up(p, d);
            if (s >= d) p *= pu;
        }
        float T = (s == 0) ? 1.f : __shfl_up(p, 1);
        float w = alpha * T;

        float* rgb_map   = out;
        float* depth_map = out + R_ * 3;
        float* weights   = out + R_ * 4;
        float* swei      = weights + N_;
        float* dwei      = swei + N_;
        weights[base + s] = w;
        swei[base + s]    = omb * w;
        dwei[base + s]    = bw * w;

        float c0 = w * cr, c1 = w * cg, c2 = w * cb, dd = w * z;
#pragma unroll
        for (int d = 32; d >= 1; d >>= 1) {
            c0 += __shfl_down(c0, d);
            c1 += __shfl_down(c1, d);
            c2 += __shfl_down(c2, d);
            dd += __shfl_down(dd, d);
        }
        if (s == 0) {
            rgb_map[ray * 3 + 0] = c0;
            rgb_map[ray * 3 + 1] = c1;
            rgb_map[ray * 3 + 2] = c2;
            depth_map[ray] = dd;
        }
    }
}

// ---- prep (IDENTICAL to R25 — verified layouts). Layout (bytes):
// [0)      sW8  3*64K fp8 FRAGMENT-MAJOR
// [196608) dW8  same
// [393216) sWinT 256*32 bf16 (k>=6 zero-padded)
// [409600) dWinT 256*32 bf16 (k>=7 zero-padded)
// [425984) sWoT8 2 tiles x 2KB fragment-major (o>=4 zero-padded)
// [430080) dWoT8 same (o>=5 zero-padded)
__global__ void convert_weights(const float* __restrict__ sWh, const float* __restrict__ dWh,
                                const float* __restrict__ sWin, const float* __restrict__ dWin,
                                const float* __restrict__ sWout, const float* __restrict__ dWout,
                                unsigned char* __restrict__ ws)
{
    int idx = blockIdx.x * 256 + threadIdx.x;      // 417792 total
    if (idx < 393216) {
        int which = idx >= 196608;
        int rem   = which ? idx - 196608 : idx;
        int l = rem >> 16, e = rem & 65535;
        int t = e >> 11, r2 = e & 2047;
        int h = r2 >> 10, r3 = r2 & 1023;
        int ln = r3 >> 4, b = r3 & 15;
        int wv = t >> 2, nt = (t >> 1) & 1, s = t & 1;
        int n = wv * 32 + nt * 16 + (ln & 15);
        int k = s * 128 + (ln >> 4) * 32 + h * 16 + b;
        const float* W = which ? dWh : sWh;
        ws[idx] = f2fp8(W[l * 65536 + k * 256 + n]);
    } else if (idx < 409600) {
        int j = idx - 393216;                      // [0, 16384)
        int which = j >= 8192;
        int e = j & 8191;
        int n = e >> 5, k = e & 31;
        int ink = which ? 7 : 6;
        const float* W = which ? dWin : sWin;
        float v = (k < ink) ? W[k * 256 + n] : 0.f;
        ((short*)(ws + 393216))[j] = (short)f2bf(v);
    } else {
        int j = idx - 409600;                      // [0, 8192)
        int which = j >= 4096;
        int e = j & 4095;
        int s = e >> 11, r2 = e & 2047;
        int h = r2 >> 10, r3 = r2 & 1023;
        int ln = r3 >> 4, b = r3 & 15;
        int o = ln & 15;
        int k = s * 128 + (ln >> 4) * 32 + h * 16 + b;
        int outd = which ? 5 : 4;
        const float* W = which ? dWout : sWout;
        float v = (o < outd) ? W[k * outd + o] : 0.f;
        ws[425984 + (which ? 4096 : 0) + e] = f2fp8(v);
    }
}

extern "C" void kernel_launch(void* const* d_in, const int* in_sizes, int n_in,
                              void* d_out, int out_size, void* d_ws, size_t ws_size,
                              hipStream_t stream)
{
    const float* points = (const float*)d_in[0];
    const float* dirs   = (const float*)d_in[1];
    const float* z_vals = (const float*)d_in[2];
    const float* timev  = (const float*)d_in[3];
    const float* sWin   = (const float*)d_in[4];
    const float* sbin   = (const float*)d_in[5];
    const float* sWh    = (const float*)d_in[6];
    const float* sbh    = (const float*)d_in[7];
    const float* sWout  = (const float*)d_in[8];
    const float* sbout  = (const float*)d_in[9];
    const float* dWin   = (const float*)d_in[10];
    const float* dbin   = (const float*)d_in[11];
    const float* dWh    = (const float*)d_in[12];
    const float* dbh    = (const float*)d_in[13];
    const float* dWout  = (const float*)d_in[14];
    const float* dbout  = (const float*)d_in[15];

    unsigned char* wsb = (unsigned char*)d_ws;

    convert_weights<<<1632, 256, 0, stream>>>(sWh, dWh, sWin, dWin, sWout, dWout, wsb);

    nerf_kernel<<<R_, 512, 0, stream>>>(
        points, dirs, z_vals, timev,
        sbin, sbh, sbout, dbin, dbh, dbout,
        wsb, (float*)d_out);
}

// Round 28
// 158.562 us; speedup vs baseline: 1.0573x; 1.0344x over previous
//
#include <hip/hip_runtime.h>

#define R_ 4096
#define S_ 64
#define H_ 256
#define N_ (R_ * S_)
#define FARD 1e10f

typedef __attribute__((ext_vector_type(4))) float f32x4;
typedef __attribute__((ext_vector_type(8))) short short8;
typedef __attribute__((ext_vector_type(8))) int i32x8;

union U8 { short8 s; uint4 u; };
union V8 { i32x8 v; uint4 q[2]; };

__device__ __forceinline__ unsigned int cvt_pk_bf16(float lo, float hi) {
    unsigned int r;
    asm("v_cvt_pk_bf16_f32 %0, %1, %2" : "=v"(r) : "v"(lo), "v"(hi));
    return r;
}
__device__ __forceinline__ unsigned short f2bf(float f) {
    unsigned int x = __float_as_uint(f);
    x += 0x7fffu + ((x >> 16) & 1u);          // RNE
    return (unsigned short)(x >> 16);
}
__device__ __forceinline__ unsigned int pk4_fp8(float a0, float a1, float a2, float a3) {
    unsigned int lo, hi;
    asm("v_cvt_pk_fp8_f32 %0, %1, %2" : "=v"(lo) : "v"(a0), "v"(a1));
    asm("v_cvt_pk_fp8_f32 %0, %1, %2" : "=v"(hi) : "v"(a2), "v"(a3));
    return (lo & 0xffffu) | (hi << 16);
}
__device__ __forceinline__ unsigned char f2fp8(float v) {
    unsigned int r;
    asm("v_cvt_pk_fp8_f32 %0, %1, %2" : "=v"(r) : "v"(v), "v"(0.0f));
    return (unsigned char)(r & 0xff);
}
__device__ __forceinline__ float sigmoidf_(float x) { return 1.0f / (1.0f + expf(-x)); }

typedef const __attribute__((address_space(1))) unsigned char* gas1;
typedef __attribute__((address_space(3))) unsigned char* las3;
// async DMA 64KB global->LDS; layout pre-baked in global (m173).
__device__ __forceinline__ void stage64k(const unsigned char* g, unsigned char* l, int tid) {
#pragma unroll
    for (int i = 0; i < 8; ++i)
        __builtin_amdgcn_global_load_lds((gas1)(g + i * 8192 + tid * 16),
                                         (las3)(l + i * 8192 + tid * 16), 16, 0, 0);
}

// FRAGMENT-MAJOR act layout (R25-verified): 8 tiles of 2KB, tile = mt*2 + s.
// Byte (h*1024 + l*16 + b) of tile (mt,s) holds act[sample = mt*16 + (l&15)]
// [k = s*128 + (l>>4)*32 + h*16 + b]. Reads = ds_read_b128 @ base + lane*16
// + imm offsets (addr-VALU ~0); round-trip with the store below verified.

// store 8 packed words (neurons n0=wv*32+nt*16+4q .. +3 of samples mt*16+m0)
__device__ __forceinline__ void store_act_frag(unsigned char* act, const unsigned int pk[8],
                                               int lane, int wv)
{
    const int m0 = lane & 15;
    const int q  = lane >> 4;
    const int sp = wv >> 2;            // which k-half (s') this wave's neurons land in
    const int c4 = (wv & 3) << 4;      // lane-group within tile
#pragma unroll
    for (int nt = 0; nt < 2; ++nt)
#pragma unroll
        for (int mt = 0; mt < 4; ++mt)
            *(unsigned int*)(act + (mt * 2 + sp) * 2048 + nt * 1024 +
                             (c4 + m0) * 16 + 4 * q) = pk[nt * 4 + mt];
}

// ---- hidden layer via MX-scaled fp8 MFMA 16x16x128 (scales = 1.0).
// A fragment-major in wbuf (tile t = wv*4 + nt*2 + s), B fragment-major in act.
// Schedule (R17/R23): compute -> sync -> stage next + store -> sync.
__device__ void hidden_layer(unsigned char* act, unsigned char* wbuf,
                             const unsigned char* __restrict__ next_panel,
                             const float* __restrict__ bias, int lane, int wv, int tid)
{
    const int m0 = lane & 15;
    const int q  = lane >> 4;
    const int nw = wv << 5;            // 32 neurons per wave

    f32x4 acc[2][4];                   // 32 AGPR
#pragma unroll
    for (int nt = 0; nt < 2; ++nt) {
        const float4 bv = *(const float4*)&bias[nw + nt * 16 + 4 * q];
#pragma unroll
        for (int mt = 0; mt < 4; ++mt) {
            acc[nt][mt][0] = bv.x; acc[nt][mt][1] = bv.y;
            acc[nt][mt][2] = bv.z; acc[nt][mt][3] = bv.w;
        }
    }

    __builtin_amdgcn_s_setprio(1);
#pragma unroll
    for (int s = 0; s < 2; ++s) {                  // K = 2 steps of 128
        V8 A[2];
#pragma unroll
        for (int nt = 0; nt < 2; ++nt) {
            const int t = wv * 4 + nt * 2 + s;
            A[nt].q[0] = *(const uint4*)(wbuf + t * 2048 + lane * 16);
            A[nt].q[1] = *(const uint4*)(wbuf + t * 2048 + 1024 + lane * 16);
        }
#pragma unroll
        for (int mt = 0; mt < 4; ++mt) {
            V8 B;
            B.q[0] = *(const uint4*)(act + (mt * 2 + s) * 2048 + lane * 16);
            B.q[1] = *(const uint4*)(act + (mt * 2 + s) * 2048 + 1024 + lane * 16);
#pragma unroll
            for (int nt = 0; nt < 2; ++nt)
                acc[nt][mt] = __builtin_amdgcn_mfma_scale_f32_16x16x128_f8f6f4(
                    A[nt].v, B.v, acc[nt][mt], 0, 0,
                    0, 0x7F7F7F7Fu, 0, 0x7F7F7F7Fu);   // E8M0 127 = x1.0
        }
    }
    __builtin_amdgcn_s_setprio(0);
    __syncthreads();                   // wbuf + act reads complete
    if (next_panel) stage64k(next_panel, wbuf, tid);   // async, drains at next barrier
    unsigned int pk[8];
#pragma unroll
    for (int nt = 0; nt < 2; ++nt)
#pragma unroll
        for (int mt = 0; mt < 4; ++mt) {
            f32x4 a = acc[nt][mt];
            pk[nt * 4 + mt] = pk4_fp8(fmaxf(a[0], 0.f), fmaxf(a[1], 0.f),
                                      fmaxf(a[2], 0.f), fmaxf(a[3], 0.f));
        }
    store_act_frag(act, pk, lane, wv);
    __syncthreads();                   // act visible; DMA drained
}

// ---- input layer COMPUTE ONLY: bf16 MFMA -> 8 packed fp8 words in regs.
__device__ void input_compute(const float* __restrict__ pts, const float* __restrict__ drs,
                              const float* __restrict__ tv,
                              const short* __restrict__ WinT, const float* __restrict__ bin,
                              unsigned int pk[8], int base, int lane, int wv)
{
    const int m0 = lane & 15;
    const int q  = lane >> 4;
    const int nw = wv << 5;

    short8 B[4];
#pragma unroll
    for (int mt = 0; mt < 4; ++mt) {
        U8 ub;
        if (q == 0) {
            const int s = base + mt * 16 + m0;
            float p0 = pts[s * 3 + 0], p1 = pts[s * 3 + 1], p2 = pts[s * 3 + 2];
            float e0 = drs[s * 3 + 0], e1 = drs[s * 3 + 1], e2 = drs[s * 3 + 2];
            float t  = tv[s];
            ub.u = make_uint4(cvt_pk_bf16(p0, p1), cvt_pk_bf16(p2, e0),
                              cvt_pk_bf16(e1, e2), cvt_pk_bf16(t, 0.f));
        } else {
            ub.u = make_uint4(0, 0, 0, 0);
        }
        B[mt] = ub.s;
    }

    f32x4 acc[2][4];
#pragma unroll
    for (int nt = 0; nt < 2; ++nt) {
        const float4 bv = *(const float4*)&bin[nw + nt * 16 + 4 * q];
#pragma unroll
        for (int mt = 0; mt < 4; ++mt) {
            acc[nt][mt][0] = bv.x; acc[nt][mt][1] = bv.y;
            acc[nt][mt][2] = bv.z; acc[nt][mt][3] = bv.w;
        }
    }
#pragma unroll
    for (int nt = 0; nt < 2; ++nt) {
        // rows k>=INK of WinT are zero, so q!=0 slices contribute 0
        short8 A = *(const short8*)&WinT[(nw + nt * 16 + m0) * 32 + 8 * q];
#pragma unroll
        for (int mt = 0; mt < 4; ++mt)
            acc[nt][mt] = __builtin_amdgcn_mfma_f32_16x16x32_bf16(A, B[mt], acc[nt][mt], 0, 0, 0);
    }
#pragma unroll
    for (int nt = 0; nt < 2; ++nt)
#pragma unroll
        for (int mt = 0; mt < 4; ++mt) {
            f32x4 a = acc[nt][mt];
            pk[nt * 4 + mt] = pk4_fp8(fmaxf(a[0], 0.f), fmaxf(a[1], 0.f),
                                      fmaxf(a[2], 0.f), fmaxf(a[3], 0.f));
        }
}

// ---- output layer via scaled 16x16x128 (2 MFMA): A = WoT8 fragment-major,
// B = act tile wv (samples 16wv..16wv+15). D: col=m0 (sample), row=4q+j (outd).
template <int OUTD>
__device__ void out_mfma(const unsigned char* act, const unsigned char* __restrict__ WoT,
                         const float* __restrict__ bout, float* o, int lane, int wv)
{
    const int q = lane >> 4;

    f32x4 acc = {0.f, 0.f, 0.f, 0.f};
#pragma unroll
    for (int s = 0; s < 2; ++s) {
        V8 A, B;
        A.q[0] = *(const uint4*)(WoT + s * 2048 + lane * 16);
        A.q[1] = *(const uint4*)(WoT + s * 2048 + 1024 + lane * 16);
        B.q[0] = *(const uint4*)(act + (wv * 2 + s) * 2048 + lane * 16);
        B.q[1] = *(const uint4*)(act + (wv * 2 + s) * 2048 + 1024 + lane * 16);
        acc = __builtin_amdgcn_mfma_scale_f32_16x16x128_f8f6f4(
            A.v, B.v, acc, 0, 0, 0, 0x7F7F7F7Fu, 0, 0x7F7F7F7Fu);
    }
    if (q == 0) {
        o[0] = acc[0] + bout[0]; o[1] = acc[1] + bout[1];
        o[2] = acc[2] + bout[2]; o[3] = acc[3] + bout[3];
    }
    if (OUTD == 5 && q == 1) o[4] = acc[0] + bout[4];
}

// 512 threads = 8 waves x 32 neurons. LDS: 64K wbuf + 16K act = 80KB exactly
// -> 2 blocks/CU = 4 waves/SIMD.
__global__ __launch_bounds__(512, 4) void nerf_kernel(
    const float* __restrict__ points, const float* __restrict__ dirs,
    const float* __restrict__ z_vals, const float* __restrict__ timev,
    const float* __restrict__ sbin, const float* __restrict__ sbh, const float* __restrict__ sbout,
    const float* __restrict__ dbin, const float* __restrict__ dbh, const float* __restrict__ dbout,
    const unsigned char* __restrict__ wsb,
    float* __restrict__ out)
{
    __shared__ __align__(16) unsigned char wbuf[65536];
    __shared__ __align__(16) unsigned char act[64 * H_];   // 16KB, in-place

    const int tid  = threadIdx.x;
    const int lane = tid & 63;
    const int wv   = tid >> 6;
    const int ray  = blockIdx.x;
    const int base = ray * 64;

    const unsigned char* sW8   = wsb;                    // 3*64K fp8 fragment-major
    const unsigned char* dW8   = wsb + 196608;
    const short* sWinT = (const short*)(wsb + 393216);   // 256*32 bf16
    const short* dWinT = (const short*)(wsb + 409600);
    const unsigned char* sWoT8 = wsb + 425984;           // 2 tiles fragment-major
    const unsigned char* dWoT8 = wsb + 430080;

    // ---- static MLP ----
    stage64k(sW8 + 0 * 65536, wbuf, tid);                // s_h0 (overlaps input)
    {
        unsigned int pk[8];
        input_compute(points, dirs, timev, sWinT, sbin, pk, base, lane, wv);
        store_act_frag(act, pk, lane, wv);
    }
    __syncthreads();                                     // act ready; s_h0 staged

    hidden_layer(act, wbuf, sW8 + 1 * 65536, sbh + 0 * H_, lane, wv, tid);
    hidden_layer(act, wbuf, sW8 + 2 * 65536, sbh + 1 * H_, lane, wv, tid);
    hidden_layer(act, wbuf, dW8 + 0 * 65536, sbh + 2 * H_, lane, wv, tid);

    // ---- phase-merge: dyn-input compute (no act dep) overlaps static-out ----
    float so[4];
    unsigned int dpk[8];
    input_compute(points, dirs, timev, dWinT, dbin, dpk, base, lane, wv);
    if (wv < 4) out_mfma<4>(act, sWoT8, sbout, so, lane, wv);
    __syncthreads();                                     // out4's act reads done
    store_act_frag(act, dpk, lane, wv);
    __syncthreads();                                     // dyn act ready (d_h0 staged)

    // ---- dynamic MLP ----
    hidden_layer(act, wbuf, dW8 + 1 * 65536, dbh + 0 * H_, lane, wv, tid);
    hidden_layer(act, wbuf, dW8 + 2 * 65536, dbh + 1 * H_, lane, wv, tid);
    hidden_layer(act, wbuf, nullptr,         dbh + 2 * H_, lane, wv, tid);

    float dox[5];
    if (wv < 4) out_mfma<5>(act, dWoT8, dbout, dox, lane, wv);
    __syncthreads();                                     // act reads done; act now dead

    // ---- stash so/do into dead act (float layout [64][9]) ----
    float* mixb = (float*)act;
    if (wv < 4) {
        const int m0 = lane & 15;
        const int q  = lane >> 4;
        const int m  = (wv << 4) + m0;
        if (q == 0) {
            mixb[m * 9 + 0] = so[0];  mixb[m * 9 + 1] = so[1];
            mixb[m * 9 + 2] = so[2];  mixb[m * 9 + 3] = so[3];
            mixb[m * 9 + 4] = dox[0]; mixb[m * 9 + 5] = dox[1];
            mixb[m * 9 + 6] = dox[2]; mixb[m * 9 + 7] = dox[3];
        }
        if (q == 1) mixb[m * 9 + 8] = dox[4];
    }
    __syncthreads();

    // ---- mix + fused render: wave 0, lane s = sample
    if (tid < 64) {
        const int s = tid;
        float so0 = mixb[s * 9 + 0], so1 = mixb[s * 9 + 1];
        float so2 = mixb[s * 9 + 2], so3 = mixb[s * 9 + 3];
        float d0 = mixb[s * 9 + 4], d1 = mixb[s * 9 + 5], d2 = mixb[s * 9 + 6];
        float d3 = mixb[s * 9 + 7], d4 = mixb[s * 9 + 8];

        float bw  = sigmoidf_(d4);
        float omb = 1.f - bw;
        float sigma = omb * so0 + bw * d0;
        float cr = omb * sigmoidf_(so1) + bw * sigmoidf_(d1);
        float cg = omb * sigmoidf_(so2) + bw * sigmoidf_(d2);
        float cb = omb * sigmoidf_(so3) + bw * sigmoidf_(d3);

        float z  = z_vals[base + s];
        float zn = __shfl_down(z, 1);
        float delta = (s < 63) ? (zn - z) : FARD;
        float ex    = fminf(-sigma * delta, 60.0f);   // finite where ref overflows
        float alpha = 1.f - expf(ex);
        float f     = 1.f - alpha + 1e-10f;
        float p = f;
#pragma unroll
        for (int d = 1; d < 64; d <<= 1) {
            float pu = __shfl_up(p, d);
            if (s >= d) p *= pu;
        }
        float T = (s == 0) ? 1.f : __shfl_up(p, 1);
        float w = alpha * T;

        float* rgb_map   = out;
        float* depth_map = out + R_ * 3;
        float* weights   = out + R_ * 4;
        float* swei      = weights + N_;
        float* dwei      = swei + N_;
        weights[base + s] = w;
        swei[base + s]    = omb * w;
        dwei[base + s]    = bw * w;

        float c0 = w * cr, c1 = w * cg, c2 = w * cb, dd = w * z;
#pragma unroll
        for (int d = 32; d >= 1; d >>= 1) {
            c0 += __shfl_down(c0, d);
            c1 += __shfl_down(c1, d);
            c2 += __shfl_down(c2, d);
            dd += __shfl_down(dd, d);
        }
        if (s == 0) {
            rgb_map[ray * 3 + 0] = c0;
            rgb_map[ray * 3 + 1] = c1;
            rgb_map[ray * 3 + 2] = c2;
            depth_map[ray] = dd;
        }
    }
}

// ---- prep. Layout (bytes):
// [0)      sW8  3*64K fp8 FRAGMENT-MAJOR (R24 layout, verified)
// [196608) dW8  same
// [393216) sWinT 256*32 bf16 (k>=6 zero-padded)
// [409600) dWinT 256*32 bf16 (k>=7 zero-padded)
// [425984) sWoT8 2 tiles x 2KB fragment-major (o>=4 zero-padded)
// [430080) dWoT8 same (o>=5 zero-padded)
__global__ void convert_weights(const float* __restrict__ sWh, const float* __restrict__ dWh,
                                const float* __restrict__ sWin, const float* __restrict__ dWin,
                                const float* __restrict__ sWout, const float* __restrict__ dWout,
                                unsigned char* __restrict__ ws)
{
    int idx = blockIdx.x * 256 + threadIdx.x;      // 417792 total
    if (idx < 393216) {
        int which = idx >= 196608;
        int rem   = which ? idx - 196608 : idx;
        int l = rem >> 16, e = rem & 65535;
        int t = e >> 11, r2 = e & 2047;
        int h = r2 >> 10, r3 = r2 & 1023;
        int ln = r3 >> 4, b = r3 & 15;
        int wv = t >> 2, nt = (t >> 1) & 1, s = t & 1;
        int n = wv * 32 + nt * 16 + (ln & 15);
        int k = s * 128 + (ln >> 4) * 32 + h * 16 + b;
        const float* W = which ? dWh : sWh;
        ws[idx] = f2fp8(W[l * 65536 + k * 256 + n]);
    } else if (idx < 409600) {
        int j = idx - 393216;                      // [0, 16384)
        int which = j >= 8192;
        int e = j & 8191;
        int n = e >> 5, k = e & 31;
        int ink = which ? 7 : 6;
        const float* W = which ? dWin : sWin;
        float v = (k < ink) ? W[k * 256 + n] : 0.f;
        ((short*)(ws + 393216))[j] = (short)f2bf(v);
    } else {
        int j = idx - 409600;                      // [0, 8192)
        int which = j >= 4096;
        int e = j & 4095;                          // dst byte within 4KB region
        int s = e >> 11, r2 = e & 2047;
        int h = r2 >> 10, r3 = r2 & 1023;
        int ln = r3 >> 4, b = r3 & 15;
        int o = ln & 15;
        int k = s * 128 + (ln >> 4) * 32 + h * 16 + b;
        int outd = which ? 5 : 4;
        const float* W = which ? dWout : sWout;
        float v = (o < outd) ? W[k * outd + o] : 0.f;
        ws[425984 + (which ? 4096 : 0) + e] = f2fp8(v);
    }
}

extern "C" void kernel_launch(void* const* d_in, const int* in_sizes, int n_in,
                              void* d_out, int out_size, void* d_ws, size_t ws_size,
                              hipStream_t stream)
{
    const float* points = (const float*)d_in[0];
    const float* dirs   = (const float*)d_in[1];
    const float* z_vals = (const float*)d_in[2];
    const float* timev  = (const float*)d_in[3];
    const float* sWin   = (const float*)d_in[4];
    const float* sbin   = (const float*)d_in[5];
    const float* sWh    = (const float*)d_in[6];
    const float* sbh    = (const float*)d_in[7];
    const float* sWout  = (const float*)d_in[8];
    const float* sbout  = (const float*)d_in[9];
    const float* dWin   = (const float*)d_in[10];
    const float* dbin   = (const float*)d_in[11];
    const float* dWh    = (const float*)d_in[12];
    const float* dbh    = (const float*)d_in[13];
    const float* dWout  = (const float*)d_in[14];
    const float* dbout  = (const float*)d_in[15];

    unsigned char* wsb = (unsigned char*)d_ws;

    convert_weights<<<1632, 256, 0, stream>>>(sWh, dWh, sWin, dWin, sWout, dWout, wsb);

    nerf_kernel<<<R_, 512, 0, stream>>>(
        points, dirs, z_vals, timev,
        sbin, sbh, sbout, dbin, dbh, dbout,
        wsb, (float*)d_out);
}